// Round 5
// baseline (826.721 us; speedup 1.0000x reference)
//
#include <hip/hip_runtime.h>

#define N_USERS   200000
#define N_ITEMS   100000
#define DIM       64
#define N_NODES   300000
#define N_EDGES   1200000
#define BIN_SHIFT 8
#define NBINS     1172            // ceil(300000/256)
#define CHUNK     4096
#define NCHUNKS   293             // ceil(1200000/4096)
#define BIN_CAP   2048            // mean edges/bin = 1024 -> huge margin
#define BGRID     1024            // fused-build grid: 4 blocks/CU guaranteed co-resident

// ---- bf16 helpers (manual RNE; no NaN inputs here) ------------------------
__device__ __forceinline__ unsigned short f2b(float f) {
    unsigned u = __float_as_uint(f);
    u += 0x7FFFu + ((u >> 16) & 1u);
    return (unsigned short)(u >> 16);
}
__device__ __forceinline__ float blo(unsigned w) { return __uint_as_float(w << 16); }
__device__ __forceinline__ float bhi(unsigned w) { return __uint_as_float(w & 0xFFFF0000u); }
__device__ __forceinline__ unsigned packbf(float lo, float hi) {
    return (unsigned)f2b(lo) | ((unsigned)f2b(hi) << 16);
}

// Grid barrier for a co-resident grid (BGRID=1024 blocks, 4/CU: threads
// 1024/2048, LDS 41/160 KB, VGPR<=128 via launch_bounds -> residency
// guaranteed, spin cannot deadlock). RELEASE on arrive + ACQUIRE on spin at
// AGENT scope handles cross-XCD visibility of the phase's plain stores.
__device__ __forceinline__ void gbar(int* bar, int phase) {
    __syncthreads();
    if (threadIdx.x == 0) {
        __hip_atomic_fetch_add(bar + phase, 1, __ATOMIC_RELEASE,
                               __HIP_MEMORY_SCOPE_AGENT);
        while (__hip_atomic_load(bar + phase, __ATOMIC_ACQUIRE,
                                 __HIP_MEMORY_SCOPE_AGENT) < (int)gridDim.x)
            __builtin_amdgcn_s_sleep(1);
    }
    __syncthreads();
}

// ---------------------------------------------------------------------------
// Fused CSR build: histogram -> bin scan/rewrite -> place -> bin counting-sort
// + fused conv (g0 = x*dis bf16). One kernel, 3 internal grid barriers;
// replaces 4 kernel launches.
__global__ __launch_bounds__(256, 4) void build_kernel(
        const int* __restrict__ row, const int* __restrict__ col,
        int* __restrict__ histG, int* __restrict__ binTot,
        int* __restrict__ bar, int* __restrict__ binStart,
        int* __restrict__ tmp, int* __restrict__ col_e,
        int* __restrict__ row_ptr, float* __restrict__ dis,
        float* __restrict__ invd,
        const float* __restrict__ ue, const float* __restrict__ ie,
        unsigned short* __restrict__ g0) {
    __shared__ int smem[2560];                 // 10.25 KB union of all phases
    int* h       = smem;                       // P0/P2: NBINS cursors
    int* hist    = smem;                       // P3
    int* lofs    = smem + 256;                 // P3
    int* colsOut = smem + 512;                 // P3: BIN_CAP ints

    // ---------------- P0: per-chunk histogram over bins -------------------
    int c = blockIdx.x;
    if (c < NCHUNKS) {
        for (int i = threadIdx.x; i < NBINS; i += 256) h[i] = 0;
        __syncthreads();
        const int4* row4 = (const int4*)row;
        int base4 = c * (CHUNK / 4);           // N_EDGES % 4 == 0
        int end4  = min(base4 + CHUNK / 4, N_EDGES / 4);
        int i0 = base4 + threadIdx.x;
        int i1 = i0 + 256, i2 = i0 + 512, i3 = i0 + 768;
        int4 r0, r1, r2, r3;
        bool v0 = i0 < end4, v1 = i1 < end4, v2 = i2 < end4, v3 = i3 < end4;
        if (v0) r0 = row4[i0];
        if (v1) r1 = row4[i1];
        if (v2) r2 = row4[i2];
        if (v3) r3 = row4[i3];
        if (v0) { atomicAdd(&h[r0.x >> BIN_SHIFT], 1); atomicAdd(&h[r0.y >> BIN_SHIFT], 1);
                  atomicAdd(&h[r0.z >> BIN_SHIFT], 1); atomicAdd(&h[r0.w >> BIN_SHIFT], 1); }
        if (v1) { atomicAdd(&h[r1.x >> BIN_SHIFT], 1); atomicAdd(&h[r1.y >> BIN_SHIFT], 1);
                  atomicAdd(&h[r1.z >> BIN_SHIFT], 1); atomicAdd(&h[r1.w >> BIN_SHIFT], 1); }
        if (v2) { atomicAdd(&h[r2.x >> BIN_SHIFT], 1); atomicAdd(&h[r2.y >> BIN_SHIFT], 1);
                  atomicAdd(&h[r2.z >> BIN_SHIFT], 1); atomicAdd(&h[r2.w >> BIN_SHIFT], 1); }
        if (v3) { atomicAdd(&h[r3.x >> BIN_SHIFT], 1); atomicAdd(&h[r3.y >> BIN_SHIFT], 1);
                  atomicAdd(&h[r3.z >> BIN_SHIFT], 1); atomicAdd(&h[r3.w >> BIN_SHIFT], 1); }
        __syncthreads();
        for (int i = threadIdx.x; i < NBINS; i += 256) {
            int v = h[i];
            histG[c * NBINS + i] = v;
            if (v) atomicAdd(&binTot[i], v);
        }
    }
    gbar(bar, 0);

    // ---------------- P1: bin prefix + chunk-scan rewrite (wave 0) --------
    if (threadIdx.x < 64) {
        int lane = threadIdx.x;
        for (int b = blockIdx.x; b < NBINS; b += BGRID) {
            int pre = 0;
            for (int i = lane; i < b; i += 64) pre += binTot[i];
#pragma unroll
            for (int off = 1; off < 64; off <<= 1) pre += __shfl_xor(pre, off, 64);
            if (lane == 0) binStart[b] = pre;
            if (b == 0 && lane == 0) binStart[NBINS] = N_EDGES;
            int carry = pre;
            for (int base = 0; base < NCHUNKS; base += 64) {
                int idx = base + lane;
                int v = (idx < NCHUNKS) ? histG[idx * NBINS + b] : 0;
                int incl = v;
                for (int off = 1; off < 64; off <<= 1) {
                    int t = __shfl_up(incl, off, 64);
                    if (lane >= off) incl += t;
                }
                if (idx < NCHUNKS) histG[idx * NBINS + b] = carry + incl - v;
                carry += __shfl(incl, 63, 64);
            }
        }
    }
    gbar(bar, 1);

    // ---------------- P2: place packed (col<<8 | row&255) into tmp --------
    if (c < NCHUNKS) {
        for (int i = threadIdx.x; i < NBINS; i += 256)
            h[i] = histG[c * NBINS + i];
        __syncthreads();
        const int4* row4 = (const int4*)row;
        const int4* col4 = (const int4*)col;
        int base4 = c * (CHUNK / 4);
        int end4  = min(base4 + CHUNK / 4, N_EDGES / 4);
        int i0 = base4 + threadIdx.x;
        int i1 = i0 + 256, i2 = i0 + 512, i3 = i0 + 768;
        int4 r0, r1, r2, r3, c0, c1, c2, c3;
        bool v0 = i0 < end4, v1 = i1 < end4, v2 = i2 < end4, v3 = i3 < end4;
        if (v0) { r0 = row4[i0]; c0 = col4[i0]; }
        if (v1) { r1 = row4[i1]; c1 = col4[i1]; }
        if (v2) { r2 = row4[i2]; c2 = col4[i2]; }
        if (v3) { r3 = row4[i3]; c3 = col4[i3]; }
        auto put = [&](int r, int cc) {
            int pos = atomicAdd(&h[r >> BIN_SHIFT], 1);
            tmp[pos] = (cc << BIN_SHIFT) | (r & 255);
        };
        if (v0) { put(r0.x, c0.x); put(r0.y, c0.y); put(r0.z, c0.z); put(r0.w, c0.w); }
        if (v1) { put(r1.x, c1.x); put(r1.y, c1.y); put(r1.z, c1.z); put(r1.w, c1.w); }
        if (v2) { put(r2.x, c2.x); put(r2.y, c2.y); put(r2.z, c2.z); put(r2.w, c2.w); }
        if (v3) { put(r3.x, c3.x); put(r3.y, c3.y); put(r3.z, c3.z); put(r3.w, c3.w); }
    }
    gbar(bar, 2);

    // ---------------- P3: per-bin counting sort + row_ptr/dis + conv ------
    for (int b = blockIdx.x; b < NBINS; b += BGRID) {
        __syncthreads();                       // protect LDS reuse across bins
        int jb = binStart[b], je = binStart[b + 1];
        int n  = je - jb;
        hist[threadIdx.x] = 0;
        __syncthreads();
        int ed[8], rk[8];
        int cnt = 0;
        for (int i = threadIdx.x; i < n && cnt < 8; i += 256) {
            int rc = tmp[jb + i];
            ed[cnt] = rc;
            rk[cnt] = atomicAdd(&hist[rc & 255], 1);
            cnt++;
        }
        __syncthreads();
        int deg = hist[threadIdx.x];
        lofs[threadIdx.x] = deg;
        __syncthreads();
        for (int off = 1; off < 256; off <<= 1) {
            int t = (threadIdx.x >= off) ? lofs[threadIdx.x - off] : 0;
            __syncthreads();
            lofs[threadIdx.x] += t;
            __syncthreads();
        }
        int myEx = lofs[threadIdx.x] - deg;
        int node = (b << BIN_SHIFT) + threadIdx.x;
        if (node < N_NODES) {
            row_ptr[node] = jb + myEx;
            float fd = (float)deg;
            dis[node]  = (deg > 0) ? rsqrtf(fd) : 0.0f;
            invd[node] = (deg > 0) ? sqrtf(fd)  : 0.0f;
        }
        if (b == 0 && threadIdx.x == 0) row_ptr[N_NODES] = N_EDGES;
        lofs[threadIdx.x] = myEx;
        __syncthreads();
        for (int k = 0; k < cnt; ++k)
            colsOut[lofs[ed[k] & 255] + rk[k]] = ((unsigned)ed[k]) >> BIN_SHIFT;
        __syncthreads();
        for (int i = threadIdx.x; i < n; i += 256)
            col_e[jb + i] = colsOut[i];

        // fused conv: g0 rows for nodes [b*256, b*256+256), 8 lanes/node
        int q = threadIdx.x & 7;
        for (int pass = 0; pass < 8; ++pass) {
            int nl = pass * 32 + (threadIdx.x >> 3);
            int nd = (b << BIN_SHIFT) + nl;
            if (nd >= N_NODES) break;
            int dg = hist[nl];
            float w = (dg > 0) ? rsqrtf((float)dg) : 0.0f;
            const float* src = (nd < N_USERS) ? (ue + nd * DIM)
                                              : (ie + (nd - N_USERS) * DIM);
            float4 x0 = ((const float4*)src)[2 * q];
            float4 x1 = ((const float4*)src)[2 * q + 1];
            uint4 o;
            o.x = packbf(w * x0.x, w * x0.y);
            o.y = packbf(w * x0.z, w * x0.w);
            o.z = packbf(w * x1.x, w * x1.y);
            o.w = packbf(w * x1.z, w * x1.w);
            ((uint4*)(g0 + nd * DIM))[q] = o;
        }
    }
}

// ---------------------------------------------------------------------------
// Atomic-free bf16 pull (exact round-0 form -- best measured: 60.3 us):
// 8 lanes/node, 16 B gathers, 4-way edge unroll.
// g_{l+1}[r] = dis_r^2 * sum g_l[c].
// FINAL: out = 0.25*(x + (g1+g2)*sqrt(deg) + dis*sum g2[c])
template <bool FINAL>
__global__ __launch_bounds__(256) void pull_kernel(
        const unsigned short* __restrict__ g_in,
        const int* __restrict__ row_ptr, const int* __restrict__ col_e,
        const float* __restrict__ dis, const float* __restrict__ invd,
        const float* __restrict__ ue, const float* __restrict__ ie,
        const unsigned short* __restrict__ gA,
        const unsigned short* __restrict__ gB,
        unsigned short* __restrict__ g_out,
        float* __restrict__ out) {
    int gid  = blockIdx.x * blockDim.x + threadIdx.x;
    int node = gid >> 3;
    int q    = gid & 7;
    if (node >= N_NODES) return;
    int jb = row_ptr[node];
    int je = row_ptr[node + 1];
    const uint4* gin4 = (const uint4*)g_in;   // row = 8 uint4

    float acc[8];
#pragma unroll
    for (int k = 0; k < 8; ++k) acc[k] = 0.f;

    auto accum = [&](uint4 u) {
        acc[0] += blo(u.x); acc[1] += bhi(u.x);
        acc[2] += blo(u.y); acc[3] += bhi(u.y);
        acc[4] += blo(u.z); acc[5] += bhi(u.z);
        acc[6] += blo(u.w); acc[7] += bhi(u.w);
    };

    int j = jb;
    for (; j + 3 < je; j += 4) {
        int c0 = col_e[j], c1 = col_e[j + 1], c2 = col_e[j + 2], c3 = col_e[j + 3];
        uint4 u0 = gin4[c0 * 8 + q];
        uint4 u1 = gin4[c1 * 8 + q];
        uint4 u2 = gin4[c2 * 8 + q];
        uint4 u3 = gin4[c3 * 8 + q];
        accum(u0); accum(u1); accum(u2); accum(u3);
    }
    for (; j < je; ++j) {
        uint4 u = gin4[col_e[j] * 8 + q];
        accum(u);
    }

    float dr = dis[node];
    if (!FINAL) {
        float s = dr * dr;
        uint4 o;
        o.x = packbf(s * acc[0], s * acc[1]);
        o.y = packbf(s * acc[2], s * acc[3]);
        o.z = packbf(s * acc[4], s * acc[5]);
        o.w = packbf(s * acc[6], s * acc[7]);
        ((uint4*)(g_out + node * DIM))[q] = o;
    } else {
        float iv = invd[node];
        const float* xs = (node < N_USERS) ? (ue + node * DIM)
                                           : (ie + (node - N_USERS) * DIM);
        float4 x0 = ((const float4*)xs)[2 * q];
        float4 x1 = ((const float4*)xs)[2 * q + 1];
        uint4 a = ((const uint4*)gA)[node * 8 + q];
        uint4 b = ((const uint4*)gB)[node * 8 + q];
        float4 o0, o1;
        o0.x = 0.25f * (x0.x + (blo(a.x) + blo(b.x)) * iv + dr * acc[0]);
        o0.y = 0.25f * (x0.y + (bhi(a.x) + bhi(b.x)) * iv + dr * acc[1]);
        o0.z = 0.25f * (x0.z + (blo(a.y) + blo(b.y)) * iv + dr * acc[2]);
        o0.w = 0.25f * (x0.w + (bhi(a.y) + bhi(b.y)) * iv + dr * acc[3]);
        o1.x = 0.25f * (x1.x + (blo(a.z) + blo(b.z)) * iv + dr * acc[4]);
        o1.y = 0.25f * (x1.y + (bhi(a.z) + bhi(b.z)) * iv + dr * acc[5]);
        o1.z = 0.25f * (x1.z + (blo(a.w) + blo(b.w)) * iv + dr * acc[6]);
        o1.w = 0.25f * (x1.w + (bhi(a.w) + bhi(b.w)) * iv + dr * acc[7]);
        ((float4*)out)[node * 16 + 2 * q]     = o0;
        ((float4*)out)[node * 16 + 2 * q + 1] = o1;
    }
}

extern "C" void kernel_launch(void* const* d_in, const int* in_sizes, int n_in,
                              void* d_out, int out_size, void* d_ws, size_t ws_size,
                              hipStream_t stream) {
    const float* ue  = (const float*)d_in[0];
    const float* ie  = (const float*)d_in[1];
    const int*   ei  = (const int*)d_in[2];
    const int*   row = ei;
    const int*   col = ei + N_EDGES;
    float*       out = (float*)d_out;

    // workspace layout (~135 MB)
    size_t gElems = (size_t)N_NODES * DIM;                 // 19.2 M
    unsigned short* g0 = (unsigned short*)d_ws;            // 38.4 MB
    unsigned short* g1 = g0 + gElems;                      // 38.4 MB
    unsigned short* g2 = g1 + gElems;                      // 38.4 MB
    int*   tmp      = (int*)(g2 + gElems);                 // 4.8 MB (packed)
    int*   col_e    = tmp + N_EDGES;                       // 4.8 MB
    int*   row_ptr  = col_e + N_EDGES;                     // 1.2 MB
    float* dis      = (float*)(row_ptr + N_NODES + 1);
    float* invd     = dis + N_NODES;
    int*   histG    = (int*)(invd + N_NODES);              // 293*1172*4 = 1.37 MB
    int*   binTot   = histG + NCHUNKS * NBINS;
    int*   bar      = binTot + NBINS;                      // 4 grid-barrier slots
    int*   binStart = bar + 4;

    const int B  = 256;
    const int GP = (N_NODES * 8 + B - 1) / B;

    // ---- fused CSR build: one memset + one kernel (was 5 launches) ----
    hipMemsetAsync(binTot, 0, (size_t)(NBINS + 4) * sizeof(int), stream);
    build_kernel<<<BGRID, B, 0, stream>>>(row, col, histG, binTot, bar, binStart,
                                          tmp, col_e, row_ptr, dis, invd,
                                          ue, ie, g0);

    // ---- 3 bf16 pull layers; acc + scale fused into the last epilogue ----
    pull_kernel<false><<<GP, B, 0, stream>>>(g0, row_ptr, col_e, dis, invd,
                                             nullptr, nullptr, nullptr, nullptr, g1, nullptr);
    pull_kernel<false><<<GP, B, 0, stream>>>(g1, row_ptr, col_e, dis, invd,
                                             nullptr, nullptr, nullptr, nullptr, g2, nullptr);
    pull_kernel<true ><<<GP, B, 0, stream>>>(g2, row_ptr, col_e, dis, invd,
                                             ue, ie, g1, g2, nullptr, out);
}

// Round 6
// 574.652 us; speedup vs baseline: 1.4386x; 1.4386x over previous
//
#include <hip/hip_runtime.h>

#define N_USERS   200000
#define N_ITEMS   100000
#define DIM       64
#define N_NODES   300000
#define N_EDGES   1200000
#define BIN_SHIFT 8
#define NBINS     1172            // ceil(300000/256)
#define CHUNK     4096
#define NCHUNKS   293             // ceil(1200000/4096)
#define BIN_CAP   2048            // mean edges/bin = 1024 -> huge margin
#define BGRID     1024            // fused-build grid: 4 blocks/CU guaranteed co-resident

// ---- bf16 helpers (manual RNE; no NaN inputs here) ------------------------
__device__ __forceinline__ unsigned short f2b(float f) {
    unsigned u = __float_as_uint(f);
    u += 0x7FFFu + ((u >> 16) & 1u);
    return (unsigned short)(u >> 16);
}
__device__ __forceinline__ float blo(unsigned w) { return __uint_as_float(w << 16); }
__device__ __forceinline__ float bhi(unsigned w) { return __uint_as_float(w & 0xFFFF0000u); }
__device__ __forceinline__ unsigned packbf(float lo, float hi) {
    return (unsigned)f2b(lo) | ((unsigned)f2b(hi) << 16);
}

// Sense-reversing grid barrier for a co-resident grid (BGRID=1024 blocks,
// 4/CU: threads 1024/2048, LDS 41/160 KB, VGPR<=128 -> residency guaranteed).
// Arrive: one ACQ_REL fetch-add (release publishes this phase's stores).
// Last arriver sets epoch flag with RELEASE. Spinners poll the flag with
// RELAXED agent-scope loads (performed at the coherence point -> always
// fresh, but NO per-poll cache invalidate) + s_sleep backoff, then issue a
// single ACQUIRE load to invalidate stale cached data. This avoids R5's
// acquire-per-poll invalidate storm (613 us -> expected ~us).
__device__ __forceinline__ void gbar(int* cnt, int* flag, int phase) {
    __syncthreads();
    if (threadIdx.x == 0) {
        int old = __hip_atomic_fetch_add(cnt, 1, __ATOMIC_ACQ_REL,
                                         __HIP_MEMORY_SCOPE_AGENT);
        if (old == (int)gridDim.x * (phase + 1) - 1) {
            __hip_atomic_store(flag, phase + 1, __ATOMIC_RELEASE,
                               __HIP_MEMORY_SCOPE_AGENT);
        } else {
            while (__hip_atomic_load(flag, __ATOMIC_RELAXED,
                                     __HIP_MEMORY_SCOPE_AGENT) <= phase)
                __builtin_amdgcn_s_sleep(32);
            (void)__hip_atomic_load(flag, __ATOMIC_ACQUIRE,
                                    __HIP_MEMORY_SCOPE_AGENT);
        }
    }
    __syncthreads();
}

// ---------------------------------------------------------------------------
// Fused CSR build: histogram -> bin scan/rewrite -> place -> bin counting-sort
// + fused conv (g0 = x*dis bf16). One kernel, 3 internal grid barriers;
// replaces 4 kernel launches.
__global__ __launch_bounds__(256, 4) void build_kernel(
        const int* __restrict__ row, const int* __restrict__ col,
        int* __restrict__ histG, int* __restrict__ binTot,
        int* __restrict__ bar, int* __restrict__ binStart,
        int* __restrict__ tmp, int* __restrict__ col_e,
        int* __restrict__ row_ptr, float* __restrict__ dis,
        float* __restrict__ invd,
        const float* __restrict__ ue, const float* __restrict__ ie,
        unsigned short* __restrict__ g0) {
    __shared__ int smem[2560];                 // 10.25 KB union of all phases
    int* h       = smem;                       // P0/P2: NBINS cursors
    int* hist    = smem;                       // P3
    int* lofs    = smem + 256;                 // P3
    int* colsOut = smem + 512;                 // P3: BIN_CAP ints
    int* cnt  = bar;                           // arrival counter (monotone)
    int* flag = bar + 1;                       // epoch flag

    // ---------------- P0: per-chunk histogram over bins -------------------
    int c = blockIdx.x;
    if (c < NCHUNKS) {
        for (int i = threadIdx.x; i < NBINS; i += 256) h[i] = 0;
        __syncthreads();
        const int4* row4 = (const int4*)row;
        int base4 = c * (CHUNK / 4);           // N_EDGES % 4 == 0
        int end4  = min(base4 + CHUNK / 4, N_EDGES / 4);
        int i0 = base4 + threadIdx.x;
        int i1 = i0 + 256, i2 = i0 + 512, i3 = i0 + 768;
        int4 r0, r1, r2, r3;
        bool v0 = i0 < end4, v1 = i1 < end4, v2 = i2 < end4, v3 = i3 < end4;
        if (v0) r0 = row4[i0];
        if (v1) r1 = row4[i1];
        if (v2) r2 = row4[i2];
        if (v3) r3 = row4[i3];
        if (v0) { atomicAdd(&h[r0.x >> BIN_SHIFT], 1); atomicAdd(&h[r0.y >> BIN_SHIFT], 1);
                  atomicAdd(&h[r0.z >> BIN_SHIFT], 1); atomicAdd(&h[r0.w >> BIN_SHIFT], 1); }
        if (v1) { atomicAdd(&h[r1.x >> BIN_SHIFT], 1); atomicAdd(&h[r1.y >> BIN_SHIFT], 1);
                  atomicAdd(&h[r1.z >> BIN_SHIFT], 1); atomicAdd(&h[r1.w >> BIN_SHIFT], 1); }
        if (v2) { atomicAdd(&h[r2.x >> BIN_SHIFT], 1); atomicAdd(&h[r2.y >> BIN_SHIFT], 1);
                  atomicAdd(&h[r2.z >> BIN_SHIFT], 1); atomicAdd(&h[r2.w >> BIN_SHIFT], 1); }
        if (v3) { atomicAdd(&h[r3.x >> BIN_SHIFT], 1); atomicAdd(&h[r3.y >> BIN_SHIFT], 1);
                  atomicAdd(&h[r3.z >> BIN_SHIFT], 1); atomicAdd(&h[r3.w >> BIN_SHIFT], 1); }
        __syncthreads();
        for (int i = threadIdx.x; i < NBINS; i += 256) {
            int v = h[i];
            histG[c * NBINS + i] = v;
            if (v) atomicAdd(&binTot[i], v);
        }
    }
    gbar(cnt, flag, 0);

    // ---------------- P1: bin prefix + chunk-scan rewrite (wave 0) --------
    if (threadIdx.x < 64) {
        int lane = threadIdx.x;
        for (int b = blockIdx.x; b < NBINS; b += BGRID) {
            int pre = 0;
            for (int i = lane; i < b; i += 64) pre += binTot[i];
#pragma unroll
            for (int off = 1; off < 64; off <<= 1) pre += __shfl_xor(pre, off, 64);
            if (lane == 0) binStart[b] = pre;
            if (b == 0 && lane == 0) binStart[NBINS] = N_EDGES;
            int carry = pre;
            for (int base = 0; base < NCHUNKS; base += 64) {
                int idx = base + lane;
                int v = (idx < NCHUNKS) ? histG[idx * NBINS + b] : 0;
                int incl = v;
                for (int off = 1; off < 64; off <<= 1) {
                    int t = __shfl_up(incl, off, 64);
                    if (lane >= off) incl += t;
                }
                if (idx < NCHUNKS) histG[idx * NBINS + b] = carry + incl - v;
                carry += __shfl(incl, 63, 64);
            }
        }
    }
    gbar(cnt, flag, 1);

    // ---------------- P2: place packed (col<<8 | row&255) into tmp --------
    if (c < NCHUNKS) {
        for (int i = threadIdx.x; i < NBINS; i += 256)
            h[i] = histG[c * NBINS + i];
        __syncthreads();
        const int4* row4 = (const int4*)row;
        const int4* col4 = (const int4*)col;
        int base4 = c * (CHUNK / 4);
        int end4  = min(base4 + CHUNK / 4, N_EDGES / 4);
        int i0 = base4 + threadIdx.x;
        int i1 = i0 + 256, i2 = i0 + 512, i3 = i0 + 768;
        int4 r0, r1, r2, r3, c0, c1, c2, c3;
        bool v0 = i0 < end4, v1 = i1 < end4, v2 = i2 < end4, v3 = i3 < end4;
        if (v0) { r0 = row4[i0]; c0 = col4[i0]; }
        if (v1) { r1 = row4[i1]; c1 = col4[i1]; }
        if (v2) { r2 = row4[i2]; c2 = col4[i2]; }
        if (v3) { r3 = row4[i3]; c3 = col4[i3]; }
        auto put = [&](int r, int cc) {
            int pos = atomicAdd(&h[r >> BIN_SHIFT], 1);
            tmp[pos] = (cc << BIN_SHIFT) | (r & 255);
        };
        if (v0) { put(r0.x, c0.x); put(r0.y, c0.y); put(r0.z, c0.z); put(r0.w, c0.w); }
        if (v1) { put(r1.x, c1.x); put(r1.y, c1.y); put(r1.z, c1.z); put(r1.w, c1.w); }
        if (v2) { put(r2.x, c2.x); put(r2.y, c2.y); put(r2.z, c2.z); put(r2.w, c2.w); }
        if (v3) { put(r3.x, c3.x); put(r3.y, c3.y); put(r3.z, c3.z); put(r3.w, c3.w); }
    }
    gbar(cnt, flag, 2);

    // ---------------- P3: per-bin counting sort + row_ptr/dis + conv ------
    for (int b = blockIdx.x; b < NBINS; b += BGRID) {
        __syncthreads();                       // protect LDS reuse across bins
        int jb = binStart[b], je = binStart[b + 1];
        int n  = je - jb;
        hist[threadIdx.x] = 0;
        __syncthreads();
        int ed[8], rk[8];
        int cnt8 = 0;
        for (int i = threadIdx.x; i < n && cnt8 < 8; i += 256) {
            int rc = tmp[jb + i];
            ed[cnt8] = rc;
            rk[cnt8] = atomicAdd(&hist[rc & 255], 1);
            cnt8++;
        }
        __syncthreads();
        int deg = hist[threadIdx.x];
        lofs[threadIdx.x] = deg;
        __syncthreads();
        for (int off = 1; off < 256; off <<= 1) {
            int t = (threadIdx.x >= off) ? lofs[threadIdx.x - off] : 0;
            __syncthreads();
            lofs[threadIdx.x] += t;
            __syncthreads();
        }
        int myEx = lofs[threadIdx.x] - deg;
        int node = (b << BIN_SHIFT) + threadIdx.x;
        if (node < N_NODES) {
            row_ptr[node] = jb + myEx;
            float fd = (float)deg;
            dis[node]  = (deg > 0) ? rsqrtf(fd) : 0.0f;
            invd[node] = (deg > 0) ? sqrtf(fd)  : 0.0f;
        }
        if (b == 0 && threadIdx.x == 0) row_ptr[N_NODES] = N_EDGES;
        lofs[threadIdx.x] = myEx;
        __syncthreads();
        for (int k = 0; k < cnt8; ++k)
            colsOut[lofs[ed[k] & 255] + rk[k]] = ((unsigned)ed[k]) >> BIN_SHIFT;
        __syncthreads();
        for (int i = threadIdx.x; i < n; i += 256)
            col_e[jb + i] = colsOut[i];

        // fused conv: g0 rows for nodes [b*256, b*256+256), 8 lanes/node
        int q = threadIdx.x & 7;
        for (int pass = 0; pass < 8; ++pass) {
            int nl = pass * 32 + (threadIdx.x >> 3);
            int nd = (b << BIN_SHIFT) + nl;
            if (nd >= N_NODES) break;
            int dg = hist[nl];
            float w = (dg > 0) ? rsqrtf((float)dg) : 0.0f;
            const float* src = (nd < N_USERS) ? (ue + nd * DIM)
                                              : (ie + (nd - N_USERS) * DIM);
            float4 x0 = ((const float4*)src)[2 * q];
            float4 x1 = ((const float4*)src)[2 * q + 1];
            uint4 o;
            o.x = packbf(w * x0.x, w * x0.y);
            o.y = packbf(w * x0.z, w * x0.w);
            o.z = packbf(w * x1.x, w * x1.y);
            o.w = packbf(w * x1.z, w * x1.w);
            ((uint4*)(g0 + nd * DIM))[q] = o;
        }
    }
}

// ---------------------------------------------------------------------------
// Atomic-free bf16 pull (exact round-0 form -- best measured: 60.3 us):
// 8 lanes/node, 16 B gathers, 4-way edge unroll.
// g_{l+1}[r] = dis_r^2 * sum g_l[c].
// FINAL: out = 0.25*(x + (g1+g2)*sqrt(deg) + dis*sum g2[c])
template <bool FINAL>
__global__ __launch_bounds__(256) void pull_kernel(
        const unsigned short* __restrict__ g_in,
        const int* __restrict__ row_ptr, const int* __restrict__ col_e,
        const float* __restrict__ dis, const float* __restrict__ invd,
        const float* __restrict__ ue, const float* __restrict__ ie,
        const unsigned short* __restrict__ gA,
        const unsigned short* __restrict__ gB,
        unsigned short* __restrict__ g_out,
        float* __restrict__ out) {
    int gid  = blockIdx.x * blockDim.x + threadIdx.x;
    int node = gid >> 3;
    int q    = gid & 7;
    if (node >= N_NODES) return;
    int jb = row_ptr[node];
    int je = row_ptr[node + 1];
    const uint4* gin4 = (const uint4*)g_in;   // row = 8 uint4

    float acc[8];
#pragma unroll
    for (int k = 0; k < 8; ++k) acc[k] = 0.f;

    auto accum = [&](uint4 u) {
        acc[0] += blo(u.x); acc[1] += bhi(u.x);
        acc[2] += blo(u.y); acc[3] += bhi(u.y);
        acc[4] += blo(u.z); acc[5] += bhi(u.z);
        acc[6] += blo(u.w); acc[7] += bhi(u.w);
    };

    int j = jb;
    for (; j + 3 < je; j += 4) {
        int c0 = col_e[j], c1 = col_e[j + 1], c2 = col_e[j + 2], c3 = col_e[j + 3];
        uint4 u0 = gin4[c0 * 8 + q];
        uint4 u1 = gin4[c1 * 8 + q];
        uint4 u2 = gin4[c2 * 8 + q];
        uint4 u3 = gin4[c3 * 8 + q];
        accum(u0); accum(u1); accum(u2); accum(u3);
    }
    for (; j < je; ++j) {
        uint4 u = gin4[col_e[j] * 8 + q];
        accum(u);
    }

    float dr = dis[node];
    if (!FINAL) {
        float s = dr * dr;
        uint4 o;
        o.x = packbf(s * acc[0], s * acc[1]);
        o.y = packbf(s * acc[2], s * acc[3]);
        o.z = packbf(s * acc[4], s * acc[5]);
        o.w = packbf(s * acc[6], s * acc[7]);
        ((uint4*)(g_out + node * DIM))[q] = o;
    } else {
        float iv = invd[node];
        const float* xs = (node < N_USERS) ? (ue + node * DIM)
                                           : (ie + (node - N_USERS) * DIM);
        float4 x0 = ((const float4*)xs)[2 * q];
        float4 x1 = ((const float4*)xs)[2 * q + 1];
        uint4 a = ((const uint4*)gA)[node * 8 + q];
        uint4 b = ((const uint4*)gB)[node * 8 + q];
        float4 o0, o1;
        o0.x = 0.25f * (x0.x + (blo(a.x) + blo(b.x)) * iv + dr * acc[0]);
        o0.y = 0.25f * (x0.y + (bhi(a.x) + bhi(b.x)) * iv + dr * acc[1]);
        o0.z = 0.25f * (x0.z + (blo(a.y) + blo(b.y)) * iv + dr * acc[2]);
        o0.w = 0.25f * (x0.w + (bhi(a.y) + bhi(b.y)) * iv + dr * acc[3]);
        o1.x = 0.25f * (x1.x + (blo(a.z) + blo(b.z)) * iv + dr * acc[4]);
        o1.y = 0.25f * (x1.y + (bhi(a.z) + bhi(b.z)) * iv + dr * acc[5]);
        o1.z = 0.25f * (x1.z + (blo(a.w) + blo(b.w)) * iv + dr * acc[6]);
        o1.w = 0.25f * (x1.w + (bhi(a.w) + bhi(b.w)) * iv + dr * acc[7]);
        ((float4*)out)[node * 16 + 2 * q]     = o0;
        ((float4*)out)[node * 16 + 2 * q + 1] = o1;
    }
}

extern "C" void kernel_launch(void* const* d_in, const int* in_sizes, int n_in,
                              void* d_out, int out_size, void* d_ws, size_t ws_size,
                              hipStream_t stream) {
    const float* ue  = (const float*)d_in[0];
    const float* ie  = (const float*)d_in[1];
    const int*   ei  = (const int*)d_in[2];
    const int*   row = ei;
    const int*   col = ei + N_EDGES;
    float*       out = (float*)d_out;

    // workspace layout (~135 MB)
    size_t gElems = (size_t)N_NODES * DIM;                 // 19.2 M
    unsigned short* g0 = (unsigned short*)d_ws;            // 38.4 MB
    unsigned short* g1 = g0 + gElems;                      // 38.4 MB
    unsigned short* g2 = g1 + gElems;                      // 38.4 MB
    int*   tmp      = (int*)(g2 + gElems);                 // 4.8 MB (packed)
    int*   col_e    = tmp + N_EDGES;                       // 4.8 MB
    int*   row_ptr  = col_e + N_EDGES;                     // 1.2 MB
    float* dis      = (float*)(row_ptr + N_NODES + 1);
    float* invd     = dis + N_NODES;
    int*   histG    = (int*)(invd + N_NODES);              // 293*1172*4 = 1.37 MB
    int*   binTot   = histG + NCHUNKS * NBINS;
    int*   bar      = binTot + NBINS;                      // [cnt, flag, pad, pad]
    int*   binStart = bar + 4;

    const int B  = 256;
    const int GP = (N_NODES * 8 + B - 1) / B;

    // ---- fused CSR build: one memset + one kernel (was 5 launches) ----
    hipMemsetAsync(binTot, 0, (size_t)(NBINS + 4) * sizeof(int), stream);
    build_kernel<<<BGRID, B, 0, stream>>>(row, col, histG, binTot, bar, binStart,
                                          tmp, col_e, row_ptr, dis, invd,
                                          ue, ie, g0);

    // ---- 3 bf16 pull layers; acc + scale fused into the last epilogue ----
    pull_kernel<false><<<GP, B, 0, stream>>>(g0, row_ptr, col_e, dis, invd,
                                             nullptr, nullptr, nullptr, nullptr, g1, nullptr);
    pull_kernel<false><<<GP, B, 0, stream>>>(g1, row_ptr, col_e, dis, invd,
                                             nullptr, nullptr, nullptr, nullptr, g2, nullptr);
    pull_kernel<true ><<<GP, B, 0, stream>>>(g2, row_ptr, col_e, dis, invd,
                                             ue, ie, g1, g2, nullptr, out);
}